// Round 1
// baseline (24848.459 us; speedup 1.0000x reference)
//
#include <hip/hip_runtime.h>
#include <math.h>

#define BGRAPH 16
#define NPG    4096
#define NPTS   (BGRAPH*NPG)   // 65536
#define KNN    20
#define NC     40
#define EPSBN  1e-5f

// ---------------- ws layout (bytes) ----------------
#define O_X0   0u               // float[NPTS*4]      1 MB
#define O_IDX  1048576u         // int[NPTS*20]       5 MB
#define O_X1   6291456u         // float[NPTS*64]     16 MB
#define O_UV   23068672u        // float[NPTS*256]    64 MB (u' cols 0..127 -> becomes x2; v cols 128..255)
#define O_WT   90177536u        // folded weights + out2enc

// ---------------- helpers ----------------
__device__ __forceinline__ unsigned encf(float v) {
    unsigned u = __float_as_uint(v);
    return (u & 0x80000000u) ? ~u : (u | 0x80000000u);
}
__device__ __forceinline__ float decf(unsigned k) {
    unsigned u = (k & 0x80000000u) ? (k ^ 0x80000000u) : ~k;
    return __uint_as_float(u);
}

// ---------------- K0: fold BN into weights, build Wuv, zero pool accumulators ----------------
__global__ void k_fold(const float* __restrict__ W1, const float* __restrict__ b1,
                       const float* __restrict__ g1, const float* __restrict__ be1,
                       const float* __restrict__ m1, const float* __restrict__ v1,
                       const float* __restrict__ W2, const float* __restrict__ b2,
                       const float* __restrict__ g2, const float* __restrict__ be2,
                       const float* __restrict__ m2, const float* __restrict__ v2,
                       const float* __restrict__ Wc,
                       float* __restrict__ W1f, float* __restrict__ b1f,
                       float* __restrict__ W2f, float* __restrict__ b2f,
                       float* __restrict__ Wuv, unsigned* __restrict__ out2enc)
{
    int t = threadIdx.x;
    for (int i = t; i < 64; i += 256) {
        float s1 = g1[i] * rsqrtf(v1[i] + EPSBN);
        b1f[i] = (b1[i] - m1[i]) * s1 + be1[i];
        float s2 = g2[i] * rsqrtf(v2[i] + EPSBN);
        b2f[i] = (b2[i] - m2[i]) * s2 + be2[i];
    }
    for (int i = t; i < 8*64; i += 256) {
        int c = i & 63;
        W1f[i] = W1[i] * (g1[c] * rsqrtf(v1[c] + EPSBN));
    }
    for (int i = t; i < 64*64; i += 256) {
        int c = i & 63;
        W2f[i] = W2[i] * (g2[c] * rsqrtf(v2[c] + EPSBN));
    }
    for (int i = t; i < 64*256; i += 256) {
        int d = i >> 8, c = i & 255;
        Wuv[i] = (c < 128) ? (Wc[d*128 + c] - Wc[(64+d)*128 + c])
                           : Wc[(64+d)*128 + (c - 128)];
    }
    for (int i = t; i < 16*1024; i += 256) out2enc[i] = 0u;
}

// ---------------- K0b: x0 = [pos | feat] ----------------
__global__ void k_x0(const float* __restrict__ pos, const float* __restrict__ feat,
                     float* __restrict__ x0)
{
    int i = blockIdx.x*256 + threadIdx.x;
    if (i < NPTS) {
        float4 v;
        v.x = pos[i*3+0]; v.y = pos[i*3+1]; v.z = pos[i*3+2]; v.w = feat[i];
        ((float4*)x0)[i] = v;
    }
}

// ---------------- K1: kNN (K=20) per graph, lexicographic (d, idx) selection ----------------
__global__ __launch_bounds__(256) void k_knn(const float* __restrict__ x0, int* __restrict__ idx)
{
    __shared__ float4 pts[1024];
    int b  = blockIdx.x >> 4;   // graph
    int rb = blockIdx.x & 15;   // row-block within graph
    int r  = b*NPG + rb*256 + threadIdx.x;
    float4 xi = ((const float4*)x0)[r];
    float sqi = xi.x*xi.x + xi.y*xi.y + xi.z*xi.z + xi.w*xi.w;

    float bd[KNN]; int bi[KNN];  // bd[0] = worst (largest d)
    #pragma unroll
    for (int t = 0; t < KNN; ++t) { bd[t] = 3.0e38f; bi[t] = 0x7FFFFFFF; }

    for (int ch = 0; ch < 4; ++ch) {
        __syncthreads();
        #pragma unroll
        for (int l = 0; l < 4; ++l)
            pts[l*256 + threadIdx.x] = ((const float4*)x0)[b*NPG + ch*1024 + l*256 + threadIdx.x];
        __syncthreads();
        for (int j = 0; j < 1024; ++j) {
            float4 xj = pts[j];
            float dot = xi.x*xj.x + xi.y*xj.y + xi.z*xj.z + xi.w*xj.w;
            float sqj = xj.x*xj.x + xj.y*xj.y + xj.z*xj.z + xj.w*xj.w;
            float d = sqi + sqj - 2.0f*dot;
            int jg = b*NPG + ch*1024 + j;
            if (d < bd[0] || (d == bd[0] && jg < bi[0])) {
                // shift-insert, all indices compile-time (stays in VGPRs)
                #pragma unroll
                for (int t = 0; t < KNN; ++t) {
                    bool last = (t == KNN-1);
                    bool mv = !last && ((d < bd[t+1]) || (d == bd[t+1] && jg < bi[t+1]));
                    if (mv) { bd[t] = bd[t+1]; bi[t] = bi[t+1]; }
                    else    { bd[t] = d;       bi[t] = jg;       break; }
                }
            }
        }
    }
    #pragma unroll
    for (int t = 0; t < KNN; ++t) idx[r*KNN + t] = bi[t];
}

// ---------------- K2: EdgeConv1 per-edge MLP 8->64->64->64, max over K ----------------
// 4 waves/block; each wave = 64 output channels, processes PPW points.
#define PPW 8
__global__ __launch_bounds__(256) void k_conv1(const float* __restrict__ x0, const int* __restrict__ idx,
        const float* __restrict__ W1f, const float* __restrict__ b1f,
        const float* __restrict__ W2f, const float* __restrict__ b2f,
        const float* __restrict__ W3,  const float* __restrict__ b3,
        float* __restrict__ x1)
{
    __shared__ float hbA[4][64];
    __shared__ float hbB[4][64];
    int w = threadIdx.x >> 6;
    int c = threadIdx.x & 63;

    float w1c[8], w2c[64], w3c[64];
    #pragma unroll
    for (int f = 0; f < 8; ++f)  w1c[f] = W1f[f*64 + c];
    #pragma unroll
    for (int d = 0; d < 64; ++d) w2c[d] = W2f[d*64 + c];
    #pragma unroll
    for (int d = 0; d < 64; ++d) w3c[d] = W3[d*64 + c];
    float b1c = b1f[c], b2c = b2f[c], b3c = b3[c];

    int pbase = (blockIdx.x*4 + w) * PPW;
    for (int pp = 0; pp < PPW; ++pp) {
        int i = pbase + pp;
        float4 xi = ((const float4*)x0)[i];
        float mx = -3.0e38f;
        for (int k = 0; k < KNN; ++k) {
            int j = idx[i*KNN + k];
            float4 xj = ((const float4*)x0)[j];
            float h = b1c + xi.x*w1c[0] + xi.y*w1c[1] + xi.z*w1c[2] + xi.w*w1c[3]
                          + (xj.x-xi.x)*w1c[4] + (xj.y-xi.y)*w1c[5]
                          + (xj.z-xi.z)*w1c[6] + (xj.w-xi.w)*w1c[7];
            h = fmaxf(h, 0.0f);
            hbA[w][c] = h;
            __syncthreads();
            float h2 = b2c;
            const float4* hv = (const float4*)&hbA[w][0];
            #pragma unroll
            for (int q = 0; q < 16; ++q) {
                float4 v = hv[q];
                h2 += v.x*w2c[4*q] + v.y*w2c[4*q+1] + v.z*w2c[4*q+2] + v.w*w2c[4*q+3];
            }
            h2 = fmaxf(h2, 0.0f);
            hbB[w][c] = h2;
            __syncthreads();
            float h3 = b3c;
            const float4* hv2 = (const float4*)&hbB[w][0];
            #pragma unroll
            for (int q = 0; q < 16; ++q) {
                float4 v = hv2[q];
                h3 += v.x*w3c[4*q] + v.y*w3c[4*q+1] + v.z*w3c[4*q+2] + v.w*w3c[4*q+3];
            }
            mx = fmaxf(mx, h3);
        }
        x1[(size_t)i*64 + c] = mx;
    }
}

// ---------------- K3: uv = x1 @ [Wu | Wv]  (u' gets +bc) ----------------
__global__ __launch_bounds__(256) void k_uv(const float* __restrict__ x1, const float* __restrict__ Wuv,
                                            const float* __restrict__ bc, float* __restrict__ uv)
{
    __shared__ float4 As[64*16];  // 64 rows x 64 cols of x1
    int m0 = blockIdx.x * 64;
    int t  = threadIdx.x;
    #pragma unroll
    for (int l = 0; l < 4; ++l) {
        int lin = l*256 + t;  // 0..1023
        As[lin] = ((const float4*)x1)[(size_t)m0*16 + lin];
    }
    __syncthreads();
    int c = t;  // 0..255
    float acc[64];
    #pragma unroll
    for (int p = 0; p < 64; ++p) acc[p] = 0.f;
    for (int dq = 0; dq < 16; ++dq) {
        float bv0 = Wuv[(dq*4+0)*256 + c];
        float bv1 = Wuv[(dq*4+1)*256 + c];
        float bv2 = Wuv[(dq*4+2)*256 + c];
        float bv3 = Wuv[(dq*4+3)*256 + c];
        #pragma unroll
        for (int p = 0; p < 64; ++p) {
            float4 a = As[p*16 + dq];
            acc[p] += a.x*bv0 + a.y*bv1 + a.z*bv2 + a.w*bv3;
        }
    }
    float badd = (c < 128) ? bc[c] : 0.0f;
    #pragma unroll
    for (int p = 0; p < 64; ++p)
        uv[(size_t)(m0+p)*256 + c] = acc[p] + badd;
}

// ---------------- K4: x2 = u' + max_k v[nbr]  (in-place into u' half of uv) ----------------
__global__ __launch_bounds__(256) void k_x2(const int* __restrict__ idx, float* __restrict__ uv)
{
    int p = blockIdx.x*2 + (threadIdx.x >> 7);
    int c = threadIdx.x & 127;
    float m = -3.0e38f;
    #pragma unroll
    for (int k = 0; k < KNN; ++k) {
        int j = idx[p*KNN + k];
        m = fmaxf(m, uv[(size_t)j*256 + 128 + c]);
    }
    uv[(size_t)p*256 + c] += m;
}

// ---------------- K5: out1 = [x1|x2] @ Wl (+bl), fused per-graph max-pool via atomicMax ----------------
__global__ __launch_bounds__(256) void k_out1(const float* __restrict__ x1, const float* __restrict__ uv,
        const float* __restrict__ Wl, const float* __restrict__ bl, unsigned* __restrict__ out2enc)
{
    __shared__ float As[64][68];
    __shared__ float Bs[64][128];
    int n0 = blockIdx.x * 128;   // 8 col-blocks
    int m0 = blockIdx.y * 64;    // 1024 row-blocks (graph-aligned: 64 | 4096)
    int t  = threadIdx.x;
    int tx = t & 15, ty = t >> 4;
    float acc[4][8];
    #pragma unroll
    for (int i = 0; i < 4; ++i)
        #pragma unroll
        for (int j = 0; j < 8; ++j) acc[i][j] = 0.f;

    for (int kc = 0; kc < 3; ++kc) {
        __syncthreads();
        {
            const float* src = (kc == 0) ? (x1 + (size_t)m0*64) : (uv + (size_t)m0*256 + (kc-1)*64);
            int sstride = (kc == 0) ? 64 : 256;
            #pragma unroll
            for (int l = 0; l < 4; ++l) {
                int lin = l*256 + t;           // 0..1023
                int row = lin >> 4, q = lin & 15;
                float4 v = *(const float4*)(src + (size_t)row*sstride + q*4);
                As[row][q*4+0] = v.x; As[row][q*4+1] = v.y;
                As[row][q*4+2] = v.z; As[row][q*4+3] = v.w;
            }
        }
        #pragma unroll
        for (int l = 0; l < 8; ++l) {
            int lin = l*256 + t;               // 0..2047
            int row = lin >> 5, q = lin & 31;
            float4 v = *(const float4*)(Wl + (size_t)(kc*64 + row)*1024 + n0 + q*4);
            *(float4*)&Bs[row][q*4] = v;
        }
        __syncthreads();
        #pragma unroll 8
        for (int kk = 0; kk < 64; ++kk) {
            float a[4], bvs[8];
            #pragma unroll
            for (int i = 0; i < 4; ++i) a[i] = As[ty*4+i][kk];
            #pragma unroll
            for (int j = 0; j < 8; ++j) bvs[j] = Bs[kk][tx*8+j];
            #pragma unroll
            for (int i = 0; i < 4; ++i)
                #pragma unroll
                for (int j = 0; j < 8; ++j) acc[i][j] += a[i]*bvs[j];
        }
    }
    // per-thread max over its 4 rows, +bias
    float cm[8];
    #pragma unroll
    for (int j = 0; j < 8; ++j) {
        float m = acc[0][j];
        #pragma unroll
        for (int i = 1; i < 4; ++i) m = fmaxf(m, acc[i][j]);
        cm[j] = m + bl[n0 + tx*8 + j];
    }
    __syncthreads();
    float* red = &As[0][0];  // reuse: [16][128]
    #pragma unroll
    for (int j = 0; j < 8; ++j) red[ty*128 + tx*8 + j] = cm[j];
    __syncthreads();
    if (ty == 0) {
        int g = m0 >> 12;  // graph id
        #pragma unroll
        for (int j = 0; j < 8; ++j) {
            int cc = tx*8 + j;
            float m = red[cc];
            #pragma unroll
            for (int r2 = 1; r2 < 16; ++r2) m = fmaxf(m, red[r2*128 + cc]);
            atomicMax(&out2enc[g*1024 + n0 + cc], encf(m));
        }
    }
}

// ---------------- K6: per-graph head MLP + log_softmax ----------------
__global__ __launch_bounds__(256) void k_head(const unsigned* __restrict__ out2enc,
        const float* __restrict__ Wa, const float* __restrict__ ba,
        const float* __restrict__ Wb, const float* __restrict__ bb,
        const float* __restrict__ Wo, const float* __restrict__ bo,
        float* __restrict__ out)
{
    __shared__ float s1[1024];
    __shared__ float s2[512];
    __shared__ float s3[256];
    __shared__ float sl[NC];
    int g = blockIdx.x, t = threadIdx.x;
    for (int i = t; i < 1024; i += 256) s1[i] = decf(out2enc[g*1024 + i]);
    __syncthreads();
    for (int cc = t; cc < 512; cc += 256) {
        float a = ba[cc];
        #pragma unroll 8
        for (int d = 0; d < 1024; ++d) a += s1[d] * Wa[(size_t)d*512 + cc];
        s2[cc] = fmaxf(a, 0.f);
    }
    __syncthreads();
    if (t < 256) {
        float a = bb[t];
        #pragma unroll 8
        for (int d = 0; d < 512; ++d) a += s2[d] * Wb[(size_t)d*256 + t];
        s3[t] = fmaxf(a, 0.f);
    }
    __syncthreads();
    if (t < NC) {
        float a = bo[t];
        #pragma unroll 8
        for (int d = 0; d < 256; ++d) a += s3[d] * Wo[d*NC + t];
        sl[t] = a;
    }
    __syncthreads();
    if (t < 64) {
        float v = (t < NC) ? sl[t] : -3.0e38f;
        float m = v;
        #pragma unroll
        for (int o2 = 32; o2 >= 1; o2 >>= 1) m = fmaxf(m, __shfl_xor(m, o2));
        float e = (t < NC) ? expf(sl[t] - m) : 0.f;
        float s = e;
        #pragma unroll
        for (int o2 = 32; o2 >= 1; o2 >>= 1) s += __shfl_xor(s, o2);
        float ls = logf(s) + m;
        if (t < NC) out[g*NC + t] = sl[t] - ls;
    }
}

// ---------------- launch ----------------
extern "C" void kernel_launch(void* const* d_in, const int* in_sizes, int n_in,
                              void* d_out, int out_size, void* d_ws, size_t ws_size,
                              hipStream_t stream)
{
    const float* pos  = (const float*)d_in[0];
    const float* feat = (const float*)d_in[1];
    const float* W1 = (const float*)d_in[2];
    const float* b1 = (const float*)d_in[3];
    const float* g1 = (const float*)d_in[4];
    const float* be1= (const float*)d_in[5];
    const float* m1 = (const float*)d_in[6];
    const float* v1 = (const float*)d_in[7];
    const float* W2 = (const float*)d_in[8];
    const float* b2 = (const float*)d_in[9];
    const float* g2 = (const float*)d_in[10];
    const float* be2= (const float*)d_in[11];
    const float* m2 = (const float*)d_in[12];
    const float* v2 = (const float*)d_in[13];
    const float* W3 = (const float*)d_in[14];
    const float* b3 = (const float*)d_in[15];
    const float* Wc = (const float*)d_in[16];
    const float* bc = (const float*)d_in[17];
    const float* Wl = (const float*)d_in[18];
    const float* bl = (const float*)d_in[19];
    const float* Wa = (const float*)d_in[20];
    const float* ba = (const float*)d_in[21];
    const float* Wb = (const float*)d_in[22];
    const float* bb = (const float*)d_in[23];
    const float* Wo = (const float*)d_in[24];
    const float* bo = (const float*)d_in[25];
    float* out = (float*)d_out;

    char* ws = (char*)d_ws;
    float* x0  = (float*)(ws + O_X0);
    int*   idx = (int*)  (ws + O_IDX);
    float* x1  = (float*)(ws + O_X1);
    float* uv  = (float*)(ws + O_UV);
    float* W1f = (float*)(ws + O_WT);
    float* b1f = W1f + 512;
    float* W2f = b1f + 64;
    float* b2f = W2f + 4096;
    float* Wuv = b2f + 64;
    unsigned* out2enc = (unsigned*)(Wuv + 64*256);

    k_fold <<<1, 256, 0, stream>>>(W1,b1,g1,be1,m1,v1, W2,b2,g2,be2,m2,v2, Wc,
                                   W1f,b1f,W2f,b2f,Wuv,out2enc);
    k_x0   <<<NPTS/256, 256, 0, stream>>>(pos, feat, x0);
    k_knn  <<<256, 256, 0, stream>>>(x0, idx);
    k_conv1<<<NPTS/(4*PPW), 256, 0, stream>>>(x0, idx, W1f, b1f, W2f, b2f, W3, b3, x1);
    k_uv   <<<NPTS/64, 256, 0, stream>>>(x1, Wuv, bc, uv);
    k_x2   <<<NPTS/2, 256, 0, stream>>>(idx, uv);
    dim3 g5(8, 1024);
    k_out1 <<<g5, 256, 0, stream>>>(x1, uv, Wl, bl, out2enc);
    k_head <<<BGRAPH, 256, 0, stream>>>(out2enc, Wa,ba,Wb,bb,Wo,bo, out);
}

// Round 2
// 22487.483 us; speedup vs baseline: 1.1050x; 1.1050x over previous
//
#include <hip/hip_runtime.h>
#include <math.h>

#define BGRAPH 16
#define NPG    4096
#define NPTS   (BGRAPH*NPG)   // 65536
#define KNN    20
#define NC     40
#define EPSBN  1e-5f
#define SEG    4

typedef _Float16 half8 __attribute__((ext_vector_type(8)));

// ---------------- ws layout (bytes) ----------------
#define O_X0   0u               // float[NPTS*4]      1 MB
#define O_IDX  1048576u         // int[NPTS*20]       5 MB
#define O_X1   6291456u         // float[NPTS*64]     16 MB
#define O_UV   23068672u        // float[NPTS*256]    64 MB (also reused earlier for knn partial lists)
#define O_WT   90177536u        // folded weights + out2enc

// ---------------- helpers ----------------
__device__ __forceinline__ unsigned encf(float v) {
    unsigned u = __float_as_uint(v);
    return (u & 0x80000000u) ? ~u : (u | 0x80000000u);
}
__device__ __forceinline__ float decf(unsigned k) {
    unsigned u = (k & 0x80000000u) ? (k ^ 0x80000000u) : ~k;
    return __uint_as_float(u);
}

// ---------------- K0: fold BN into weights, build Wuv, zero pool accumulators ----------------
__global__ void k_fold(const float* __restrict__ W1, const float* __restrict__ b1,
                       const float* __restrict__ g1, const float* __restrict__ be1,
                       const float* __restrict__ m1, const float* __restrict__ v1,
                       const float* __restrict__ W2, const float* __restrict__ b2,
                       const float* __restrict__ g2, const float* __restrict__ be2,
                       const float* __restrict__ m2, const float* __restrict__ v2,
                       const float* __restrict__ Wc,
                       float* __restrict__ W1f, float* __restrict__ b1f,
                       float* __restrict__ W2f, float* __restrict__ b2f,
                       float* __restrict__ Wuv, unsigned* __restrict__ out2enc)
{
    int t = threadIdx.x;
    for (int i = t; i < 64; i += 256) {
        float s1 = g1[i] * rsqrtf(v1[i] + EPSBN);
        b1f[i] = (b1[i] - m1[i]) * s1 + be1[i];
        float s2 = g2[i] * rsqrtf(v2[i] + EPSBN);
        b2f[i] = (b2[i] - m2[i]) * s2 + be2[i];
    }
    for (int i = t; i < 8*64; i += 256) {
        int c = i & 63;
        W1f[i] = W1[i] * (g1[c] * rsqrtf(v1[c] + EPSBN));
    }
    for (int i = t; i < 64*64; i += 256) {
        int c = i & 63;
        W2f[i] = W2[i] * (g2[c] * rsqrtf(v2[c] + EPSBN));
    }
    for (int i = t; i < 64*256; i += 256) {
        int d = i >> 8, c = i & 255;
        Wuv[i] = (c < 128) ? (Wc[d*128 + c] - Wc[(64+d)*128 + c])
                           : Wc[(64+d)*128 + (c - 128)];
    }
    for (int i = t; i < 16*1024; i += 256) out2enc[i] = 0u;
}

// ---------------- K0b: x0 = [pos | feat] ----------------
__global__ void k_x0(const float* __restrict__ pos, const float* __restrict__ feat,
                     float* __restrict__ x0)
{
    int i = blockIdx.x*256 + threadIdx.x;
    if (i < NPTS) {
        float4 v;
        v.x = pos[i*3+0]; v.y = pos[i*3+1]; v.z = pos[i*3+2]; v.w = feat[i];
        ((float4*)x0)[i] = v;
    }
}

// ---------------- K1a: segmented kNN partials ----------------
// block = (graph b, row-block rb, segment s); each thread = one query row,
// scans the segment's 1024 points (LDS-resident) keeping lexicographic (d,idx) top-20.
__global__ __launch_bounds__(256) void k_knn_part(const float* __restrict__ x0,
        float* __restrict__ pd, int* __restrict__ pi)
{
    __shared__ float4 pts[1024];
    __shared__ float  sqs[1024];
    int x  = blockIdx.x;
    int b  = x >> 6;
    int rb = (x >> 2) & 15;
    int s  = x & 3;
    int t  = threadIdx.x;
    int r  = b*NPG + rb*256 + t;
    float4 xi = ((const float4*)x0)[r];
    float sqi = xi.x*xi.x + xi.y*xi.y + xi.z*xi.z + xi.w*xi.w;
    #pragma unroll
    for (int l = 0; l < 4; ++l) {
        float4 v = ((const float4*)x0)[b*NPG + s*1024 + l*256 + t];
        pts[l*256 + t] = v;
        sqs[l*256 + t] = v.x*v.x + v.y*v.y + v.z*v.z + v.w*v.w;
    }
    __syncthreads();

    float bd[KNN]; int bi[KNN];   // bd[0] = worst (largest)
    #pragma unroll
    for (int q = 0; q < KNN; ++q) { bd[q] = 3.0e38f; bi[q] = 0x7FFFFFFF; }
    int jbase = b*NPG + s*1024;
    for (int j = 0; j < 1024; ++j) {
        float4 xj = pts[j];
        float dot = xi.x*xj.x + xi.y*xj.y + xi.z*xj.z + xi.w*xj.w;
        float sqj = sqs[j];
        float d = sqi + sqj - 2.0f*dot;
        int jg = jbase + j;
        if (d < bd[0] || (d == bd[0] && jg < bi[0])) {
            #pragma unroll
            for (int q = 0; q < KNN; ++q) {
                bool last = (q == KNN-1);
                bool mv = !last && ((d < bd[q+1]) || (d == bd[q+1] && jg < bi[q+1]));
                if (mv) { bd[q] = bd[q+1]; bi[q] = bi[q+1]; }
                else    { bd[q] = d;       bi[q] = jg;       break; }
            }
        }
    }
    // store ascending (q=0 smallest), coalesced layout [(s*20+q)][r]
    #pragma unroll
    for (int q = 0; q < KNN; ++q) {
        pd[(size_t)(s*KNN + q)*NPTS + r] = bd[KNN-1-q];
        pi[(size_t)(s*KNN + q)*NPTS + r] = bi[KNN-1-q];
    }
}

// ---------------- K1b: merge 4 sorted partial lists -> final 20 (set only; order free) --------
__global__ __launch_bounds__(256) void k_knn_merge(const float* __restrict__ pd,
        const int* __restrict__ pi, int* __restrict__ idx)
{
    int r = blockIdx.x*256 + threadIdx.x;
    float bd[KNN]; int bi[KNN];
    #pragma unroll
    for (int q = 0; q < KNN; ++q) {
        bd[KNN-1-q] = pd[(size_t)q*NPTS + r];
        bi[KNN-1-q] = pi[(size_t)q*NPTS + r];
    }
    for (int s = 1; s < SEG; ++s) {
        #pragma unroll 1
        for (int q = 0; q < KNN; ++q) {
            float d = pd[(size_t)(s*KNN + q)*NPTS + r];
            int  jg = pi[(size_t)(s*KNN + q)*NPTS + r];
            if (d < bd[0] || (d == bd[0] && jg < bi[0])) {
                #pragma unroll
                for (int p = 0; p < KNN; ++p) {
                    bool last = (p == KNN-1);
                    bool mv = !last && ((d < bd[p+1]) || (d == bd[p+1] && jg < bi[p+1]));
                    if (mv) { bd[p] = bd[p+1]; bi[p] = bi[p+1]; }
                    else    { bd[p] = d;       bi[p] = jg;       break; }
                }
            } else break;  // sublist ascending -> rest also fails
        }
    }
    #pragma unroll
    for (int q = 0; q < KNN; ++q) idx[(size_t)r*KNN + q] = bi[q];
}

// ---------------- K2: EdgeConv1, one wave per block, fp16 LDS staging ----------------
// lane = output channel c; weights in VGPRs; h1/h2 staged per-edge in LDS fp16.
#define PTS 16
__global__ __launch_bounds__(64) void k_conv1(const float* __restrict__ x0, const int* __restrict__ idx,
        const float* __restrict__ W1f, const float* __restrict__ b1f,
        const float* __restrict__ W2f, const float* __restrict__ b2f,
        const float* __restrict__ W3,  const float* __restrict__ b3,
        float* __restrict__ x1)
{
    __shared__ _Float16 hs0[20*64];
    __shared__ _Float16 hs1[20*64];
    int c = threadIdx.x;
    float w1c[8], w2c[64], w3c[64];
    #pragma unroll
    for (int f = 0; f < 8; ++f)  w1c[f] = W1f[f*64 + c];
    #pragma unroll
    for (int d = 0; d < 64; ++d) w2c[d] = W2f[d*64 + c];
    #pragma unroll
    for (int d = 0; d < 64; ++d) w3c[d] = W3[d*64 + c];
    float b1c = b1f[c], b2c = b2f[c], b3c = b3[c];

    #pragma unroll 1
    for (int pp = 0; pp < PTS; ++pp) {
        int i = blockIdx.x*PTS + pp;
        float4 xi = ((const float4*)x0)[i];
        #pragma unroll 4
        for (int k = 0; k < KNN; ++k) {
            int j = idx[i*KNN + k];
            float4 xj = ((const float4*)x0)[j];
            float h = b1c + xi.x*w1c[0] + xi.y*w1c[1] + xi.z*w1c[2] + xi.w*w1c[3]
                          + (xj.x-xi.x)*w1c[4] + (xj.y-xi.y)*w1c[5]
                          + (xj.z-xi.z)*w1c[6] + (xj.w-xi.w)*w1c[7];
            hs0[k*64 + c] = (_Float16)fmaxf(h, 0.0f);
        }
        __syncthreads();
        // L2: h2 = relu(h1 @ W2f + b2f), 5 parallel accumulator chains
        #pragma unroll 1
        for (int kc = 0; kc < 4; ++kc) {
            float acc[5];
            #pragma unroll
            for (int k5 = 0; k5 < 5; ++k5) acc[k5] = b2c;
            #pragma unroll
            for (int q = 0; q < 8; ++q) {
                #pragma unroll
                for (int k5 = 0; k5 < 5; ++k5) {
                    half8 hv = *(const half8*)&hs0[(kc*5 + k5)*64 + q*8];
                    #pragma unroll
                    for (int jj = 0; jj < 8; ++jj)
                        acc[k5] = fmaf((float)hv[jj], w2c[q*8 + jj], acc[k5]);
                }
            }
            #pragma unroll
            for (int k5 = 0; k5 < 5; ++k5)
                hs1[(kc*5 + k5)*64 + c] = (_Float16)fmaxf(acc[k5], 0.0f);
        }
        __syncthreads();
        // L3: h3 = h2 @ W3 + b3 (no relu), max over k
        float mx = -3.0e38f;
        #pragma unroll 1
        for (int kc = 0; kc < 4; ++kc) {
            float acc[5];
            #pragma unroll
            for (int k5 = 0; k5 < 5; ++k5) acc[k5] = b3c;
            #pragma unroll
            for (int q = 0; q < 8; ++q) {
                #pragma unroll
                for (int k5 = 0; k5 < 5; ++k5) {
                    half8 hv = *(const half8*)&hs1[(kc*5 + k5)*64 + q*8];
                    #pragma unroll
                    for (int jj = 0; jj < 8; ++jj)
                        acc[k5] = fmaf((float)hv[jj], w3c[q*8 + jj], acc[k5]);
                }
            }
            #pragma unroll
            for (int k5 = 0; k5 < 5; ++k5) mx = fmaxf(mx, acc[k5]);
        }
        x1[(size_t)i*64 + c] = mx;
        __syncthreads();
    }
}

// ---------------- K3: uv = x1 @ [Wu | Wv]  (u' gets +bc) ----------------
__global__ __launch_bounds__(256) void k_uv(const float* __restrict__ x1, const float* __restrict__ Wuv,
                                            const float* __restrict__ bc, float* __restrict__ uv)
{
    __shared__ float4 As[64*16];  // 64 rows x 64 cols of x1
    int m0 = blockIdx.x * 64;
    int t  = threadIdx.x;
    #pragma unroll
    for (int l = 0; l < 4; ++l) {
        int lin = l*256 + t;  // 0..1023
        As[lin] = ((const float4*)x1)[(size_t)m0*16 + lin];
    }
    __syncthreads();
    int c = t;  // 0..255
    float acc[64];
    #pragma unroll
    for (int p = 0; p < 64; ++p) acc[p] = 0.f;
    for (int dq = 0; dq < 16; ++dq) {
        float bv0 = Wuv[(dq*4+0)*256 + c];
        float bv1 = Wuv[(dq*4+1)*256 + c];
        float bv2 = Wuv[(dq*4+2)*256 + c];
        float bv3 = Wuv[(dq*4+3)*256 + c];
        #pragma unroll
        for (int p = 0; p < 64; ++p) {
            float4 a = As[p*16 + dq];
            acc[p] += a.x*bv0 + a.y*bv1 + a.z*bv2 + a.w*bv3;
        }
    }
    float badd = (c < 128) ? bc[c] : 0.0f;
    #pragma unroll
    for (int p = 0; p < 64; ++p)
        uv[(size_t)(m0+p)*256 + c] = acc[p] + badd;
}

// ---------------- K4: x2 = u' + max_k v[nbr]  (in-place into u' half of uv) ----------------
__global__ __launch_bounds__(256) void k_x2(const int* __restrict__ idx, float* __restrict__ uv)
{
    int p = blockIdx.x*2 + (threadIdx.x >> 7);
    int c = threadIdx.x & 127;
    float m = -3.0e38f;
    #pragma unroll
    for (int k = 0; k < KNN; ++k) {
        int j = idx[p*KNN + k];
        m = fmaxf(m, uv[(size_t)j*256 + 128 + c]);
    }
    uv[(size_t)p*256 + c] += m;
}

// ---------------- K5: out1 = [x1|x2] @ Wl (+bl), fused per-graph max-pool via atomicMax ----------------
__global__ __launch_bounds__(256) void k_out1(const float* __restrict__ x1, const float* __restrict__ uv,
        const float* __restrict__ Wl, const float* __restrict__ bl, unsigned* __restrict__ out2enc)
{
    __shared__ float As[64][68];
    __shared__ float Bs[64][128];
    int n0 = blockIdx.x * 128;   // 8 col-blocks
    int m0 = blockIdx.y * 64;    // 1024 row-blocks (graph-aligned: 64 | 4096)
    int t  = threadIdx.x;
    int tx = t & 15, ty = t >> 4;
    float acc[4][8];
    #pragma unroll
    for (int i = 0; i < 4; ++i)
        #pragma unroll
        for (int j = 0; j < 8; ++j) acc[i][j] = 0.f;

    for (int kc = 0; kc < 3; ++kc) {
        __syncthreads();
        {
            const float* src = (kc == 0) ? (x1 + (size_t)m0*64) : (uv + (size_t)m0*256 + (kc-1)*64);
            int sstride = (kc == 0) ? 64 : 256;
            #pragma unroll
            for (int l = 0; l < 4; ++l) {
                int lin = l*256 + t;           // 0..1023
                int row = lin >> 4, q = lin & 15;
                float4 v = *(const float4*)(src + (size_t)row*sstride + q*4);
                As[row][q*4+0] = v.x; As[row][q*4+1] = v.y;
                As[row][q*4+2] = v.z; As[row][q*4+3] = v.w;
            }
        }
        #pragma unroll
        for (int l = 0; l < 8; ++l) {
            int lin = l*256 + t;               // 0..2047
            int row = lin >> 5, q = lin & 31;
            float4 v = *(const float4*)(Wl + (size_t)(kc*64 + row)*1024 + n0 + q*4);
            *(float4*)&Bs[row][q*4] = v;
        }
        __syncthreads();
        #pragma unroll 8
        for (int kk = 0; kk < 64; ++kk) {
            float a[4], bvs[8];
            #pragma unroll
            for (int i = 0; i < 4; ++i) a[i] = As[ty*4+i][kk];
            #pragma unroll
            for (int j = 0; j < 8; ++j) bvs[j] = Bs[kk][tx*8+j];
            #pragma unroll
            for (int i = 0; i < 4; ++i)
                #pragma unroll
                for (int j = 0; j < 8; ++j) acc[i][j] += a[i]*bvs[j];
        }
    }
    // per-thread max over its 4 rows, +bias
    float cm[8];
    #pragma unroll
    for (int j = 0; j < 8; ++j) {
        float m = acc[0][j];
        #pragma unroll
        for (int i = 1; i < 4; ++i) m = fmaxf(m, acc[i][j]);
        cm[j] = m + bl[n0 + tx*8 + j];
    }
    __syncthreads();
    float* red = &As[0][0];  // reuse: [16][128]
    #pragma unroll
    for (int j = 0; j < 8; ++j) red[ty*128 + tx*8 + j] = cm[j];
    __syncthreads();
    if (ty == 0) {
        int g = m0 >> 12;  // graph id
        #pragma unroll
        for (int j = 0; j < 8; ++j) {
            int cc = tx*8 + j;
            float m = red[cc];
            #pragma unroll
            for (int r2 = 1; r2 < 16; ++r2) m = fmaxf(m, red[r2*128 + cc]);
            atomicMax(&out2enc[g*1024 + n0 + cc], encf(m));
        }
    }
}

// ---------------- K6: per-graph head MLP + log_softmax ----------------
__global__ __launch_bounds__(256) void k_head(const unsigned* __restrict__ out2enc,
        const float* __restrict__ Wa, const float* __restrict__ ba,
        const float* __restrict__ Wb, const float* __restrict__ bb,
        const float* __restrict__ Wo, const float* __restrict__ bo,
        float* __restrict__ out)
{
    __shared__ float s1[1024];
    __shared__ float s2[512];
    __shared__ float s3[256];
    __shared__ float sl[NC];
    int g = blockIdx.x, t = threadIdx.x;
    for (int i = t; i < 1024; i += 256) s1[i] = decf(out2enc[g*1024 + i]);
    __syncthreads();
    for (int cc = t; cc < 512; cc += 256) {
        float a = ba[cc];
        #pragma unroll 8
        for (int d = 0; d < 1024; ++d) a += s1[d] * Wa[(size_t)d*512 + cc];
        s2[cc] = fmaxf(a, 0.f);
    }
    __syncthreads();
    if (t < 256) {
        float a = bb[t];
        #pragma unroll 8
        for (int d = 0; d < 512; ++d) a += s2[d] * Wb[(size_t)d*256 + t];
        s3[t] = fmaxf(a, 0.f);
    }
    __syncthreads();
    if (t < NC) {
        float a = bo[t];
        #pragma unroll 8
        for (int d = 0; d < 256; ++d) a += s3[d] * Wo[d*NC + t];
        sl[t] = a;
    }
    __syncthreads();
    if (t < 64) {
        float v = (t < NC) ? sl[t] : -3.0e38f;
        float m = v;
        #pragma unroll
        for (int o2 = 32; o2 >= 1; o2 >>= 1) m = fmaxf(m, __shfl_xor(m, o2));
        float e = (t < NC) ? expf(sl[t] - m) : 0.f;
        float s = e;
        #pragma unroll
        for (int o2 = 32; o2 >= 1; o2 >>= 1) s += __shfl_xor(s, o2);
        float ls = logf(s) + m;
        if (t < NC) out[g*NC + t] = sl[t] - ls;
    }
}

// ---------------- launch ----------------
extern "C" void kernel_launch(void* const* d_in, const int* in_sizes, int n_in,
                              void* d_out, int out_size, void* d_ws, size_t ws_size,
                              hipStream_t stream)
{
    const float* pos  = (const float*)d_in[0];
    const float* feat = (const float*)d_in[1];
    const float* W1 = (const float*)d_in[2];
    const float* b1 = (const float*)d_in[3];
    const float* g1 = (const float*)d_in[4];
    const float* be1= (const float*)d_in[5];
    const float* m1 = (const float*)d_in[6];
    const float* v1 = (const float*)d_in[7];
    const float* W2 = (const float*)d_in[8];
    const float* b2 = (const float*)d_in[9];
    const float* g2 = (const float*)d_in[10];
    const float* be2= (const float*)d_in[11];
    const float* m2 = (const float*)d_in[12];
    const float* v2 = (const float*)d_in[13];
    const float* W3 = (const float*)d_in[14];
    const float* b3 = (const float*)d_in[15];
    const float* Wc = (const float*)d_in[16];
    const float* bc = (const float*)d_in[17];
    const float* Wl = (const float*)d_in[18];
    const float* bl = (const float*)d_in[19];
    const float* Wa = (const float*)d_in[20];
    const float* ba = (const float*)d_in[21];
    const float* Wb = (const float*)d_in[22];
    const float* bb = (const float*)d_in[23];
    const float* Wo = (const float*)d_in[24];
    const float* bo = (const float*)d_in[25];
    float* out = (float*)d_out;

    char* ws = (char*)d_ws;
    float* x0  = (float*)(ws + O_X0);
    int*   idx = (int*)  (ws + O_IDX);
    float* x1  = (float*)(ws + O_X1);
    float* uv  = (float*)(ws + O_UV);
    // knn partial lists overlay the (not-yet-written) uv region
    float* pd  = (float*)(ws + O_UV);
    int*   pi  = (int*)(ws + O_UV) + (size_t)SEG*KNN*NPTS;
    float* W1f = (float*)(ws + O_WT);
    float* b1f = W1f + 512;
    float* W2f = b1f + 64;
    float* b2f = W2f + 4096;
    float* Wuv = b2f + 64;
    unsigned* out2enc = (unsigned*)(Wuv + 64*256);

    k_fold <<<1, 256, 0, stream>>>(W1,b1,g1,be1,m1,v1, W2,b2,g2,be2,m2,v2, Wc,
                                   W1f,b1f,W2f,b2f,Wuv,out2enc);
    k_x0   <<<NPTS/256, 256, 0, stream>>>(pos, feat, x0);
    k_knn_part <<<BGRAPH*16*SEG, 256, 0, stream>>>(x0, pd, pi);
    k_knn_merge<<<NPTS/256, 256, 0, stream>>>(pd, pi, idx);
    k_conv1<<<NPTS/PTS, 64, 0, stream>>>(x0, idx, W1f, b1f, W2f, b2f, W3, b3, x1);
    k_uv   <<<NPTS/64, 256, 0, stream>>>(x1, Wuv, bc, uv);
    k_x2   <<<NPTS/2, 256, 0, stream>>>(idx, uv);
    dim3 g5(8, 1024);
    k_out1 <<<g5, 256, 0, stream>>>(x1, uv, Wl, bl, out2enc);
    k_head <<<BGRAPH, 256, 0, stream>>>(out2enc, Wa,ba,Wb,bb,Wo,bo, out);
}

// Round 3
// 4053.097 us; speedup vs baseline: 6.1307x; 5.5482x over previous
//
#include <hip/hip_runtime.h>
#include <math.h>

#define BGRAPH 16
#define NPG    4096
#define NPTS   (BGRAPH*NPG)   // 65536
#define KNN    20
#define NC     40
#define EPSBN  1e-5f
#define SEG    4

typedef _Float16 half8 __attribute__((ext_vector_type(8)));
typedef unsigned long long u64;

// ---------------- ws layout (bytes) ----------------
#define O_X0   0u               // float[NPTS*4]      1 MB
#define O_IDX  1048576u         // int[NPTS*20]       5 MB
#define O_X1   6291456u         // float[NPTS*64]     16 MB
#define O_UV   23068672u        // float[NPTS*256]    64 MB (knn packed partial lists overlay this)
#define O_WT   90177536u        // folded weights + out2enc

// ---------------- helpers ----------------
__device__ __forceinline__ unsigned encf(float v) {
    unsigned u = __float_as_uint(v);
    return (u & 0x80000000u) ? ~u : (u | 0x80000000u);
}
__device__ __forceinline__ float decf(unsigned k) {
    unsigned u = (k & 0x80000000u) ? (k ^ 0x80000000u) : ~k;
    return __uint_as_float(u);
}
// monotone orderable uint from float (handles negatives)
__device__ __forceinline__ unsigned ordf(float f) {
    unsigned u = __float_as_uint(f);
    return u ^ (((unsigned)((int)u >> 31)) | 0x80000000u);
}

// branchless insert of cand into descending-quality list ck[0]=worst..ck[KNN-1]=best
__device__ __forceinline__ void topk_insert(u64* ck, u64 cand) {
    bool bt[KNN];
    #pragma unroll
    for (int t = 0; t < KNN; ++t) bt[t] = cand < ck[t];
    #pragma unroll
    for (int t = 0; t < KNN-1; ++t)
        ck[t] = bt[t+1] ? ck[t+1] : (bt[t] ? cand : ck[t]);
    ck[KNN-1] = bt[KNN-1] ? cand : ck[KNN-1];
}

// ---------------- K0: fold BN into weights, build Wuv, zero pool accumulators ----------------
__global__ void k_fold(const float* __restrict__ W1, const float* __restrict__ b1,
                       const float* __restrict__ g1, const float* __restrict__ be1,
                       const float* __restrict__ m1, const float* __restrict__ v1,
                       const float* __restrict__ W2, const float* __restrict__ b2,
                       const float* __restrict__ g2, const float* __restrict__ be2,
                       const float* __restrict__ m2, const float* __restrict__ v2,
                       const float* __restrict__ Wc,
                       float* __restrict__ W1f, float* __restrict__ b1f,
                       float* __restrict__ W2f, float* __restrict__ b2f,
                       float* __restrict__ Wuv, unsigned* __restrict__ out2enc)
{
    int t = threadIdx.x;
    for (int i = t; i < 64; i += 256) {
        float s1 = g1[i] * rsqrtf(v1[i] + EPSBN);
        b1f[i] = (b1[i] - m1[i]) * s1 + be1[i];
        float s2 = g2[i] * rsqrtf(v2[i] + EPSBN);
        b2f[i] = (b2[i] - m2[i]) * s2 + be2[i];
    }
    for (int i = t; i < 8*64; i += 256) {
        int c = i & 63;
        W1f[i] = W1[i] * (g1[c] * rsqrtf(v1[c] + EPSBN));
    }
    for (int i = t; i < 64*64; i += 256) {
        int c = i & 63;
        W2f[i] = W2[i] * (g2[c] * rsqrtf(v2[c] + EPSBN));
    }
    for (int i = t; i < 64*256; i += 256) {
        int d = i >> 8, c = i & 255;
        Wuv[i] = (c < 128) ? (Wc[d*128 + c] - Wc[(64+d)*128 + c])
                           : Wc[(64+d)*128 + (c - 128)];
    }
    for (int i = t; i < 16*1024; i += 256) out2enc[i] = 0u;
}

// ---------------- K0b: x0 = [pos | feat] ----------------
__global__ void k_x0(const float* __restrict__ pos, const float* __restrict__ feat,
                     float* __restrict__ x0)
{
    int i = blockIdx.x*256 + threadIdx.x;
    if (i < NPTS) {
        float4 v;
        v.x = pos[i*3+0]; v.y = pos[i*3+1]; v.z = pos[i*3+2]; v.w = feat[i];
        ((float4*)x0)[i] = v;
    }
}

// ---------------- K1a: segmented kNN partials (branchless u64-key top-20) ----------------
__global__ __launch_bounds__(256) void k_knn_part(const float* __restrict__ x0,
        u64* __restrict__ pk)
{
    __shared__ float4 pts[1024];
    __shared__ float  sqs[1024];
    int x  = blockIdx.x;
    int b  = x >> 6;
    int rb = (x >> 2) & 15;
    int s  = x & 3;
    int t  = threadIdx.x;
    int r  = b*NPG + rb*256 + t;
    float4 xi = ((const float4*)x0)[r];
    float sqi = xi.x*xi.x + xi.y*xi.y + xi.z*xi.z + xi.w*xi.w;
    #pragma unroll
    for (int l = 0; l < 4; ++l) {
        float4 v = ((const float4*)x0)[b*NPG + s*1024 + l*256 + t];
        pts[l*256 + t] = v;
        sqs[l*256 + t] = v.x*v.x + v.y*v.y + v.z*v.z + v.w*v.w;
    }
    __syncthreads();

    u64 ck[KNN];
    #pragma unroll
    for (int q = 0; q < KNN; ++q) ck[q] = 0xFFFFFFFFFFFFFFFFull;
    int jbase = b*NPG + s*1024;
    for (int j = 0; j < 1024; ++j) {
        float4 xj = pts[j];
        float dot = xi.x*xj.x + xi.y*xj.y + xi.z*xj.z + xi.w*xj.w;
        float sqj = sqs[j];
        float d = sqi + sqj - 2.0f*dot;
        u64 cand = ((u64)ordf(d) << 32) | (unsigned)(jbase + j);
        topk_insert(ck, cand);
    }
    #pragma unroll
    for (int q = 0; q < KNN; ++q)
        pk[(size_t)(s*KNN + q)*NPTS + r] = ck[q];
}

// ---------------- K1b: merge 4 partial lists -> final 20 indices (set only) --------
__global__ __launch_bounds__(256) void k_knn_merge(const u64* __restrict__ pk,
        int* __restrict__ idx)
{
    int r = blockIdx.x*256 + threadIdx.x;
    u64 ck[KNN];
    #pragma unroll
    for (int q = 0; q < KNN; ++q) ck[q] = pk[(size_t)q*NPTS + r];
    #pragma unroll 1
    for (int s = 1; s < SEG; ++s) {
        #pragma unroll 4
        for (int q = 0; q < KNN; ++q) {
            u64 cand = pk[(size_t)(s*KNN + q)*NPTS + r];
            topk_insert(ck, cand);
        }
    }
    #pragma unroll
    for (int q = 0; q < KNN; ++q)
        idx[(size_t)r*KNN + q] = (int)(unsigned)ck[q];
}

// ---------------- K2: EdgeConv1, one wave per block, fp16 LDS staging ----------------
#define PTS 16
__global__ __launch_bounds__(64) void k_conv1(const float* __restrict__ x0, const int* __restrict__ idx,
        const float* __restrict__ W1f, const float* __restrict__ b1f,
        const float* __restrict__ W2f, const float* __restrict__ b2f,
        const float* __restrict__ W3,  const float* __restrict__ b3,
        float* __restrict__ x1)
{
    __shared__ _Float16 hs0[20*64];
    __shared__ _Float16 hs1[20*64];
    int c = threadIdx.x;
    float w1c[8], w2c[64], w3c[64];
    #pragma unroll
    for (int f = 0; f < 8; ++f)  w1c[f] = W1f[f*64 + c];
    #pragma unroll
    for (int d = 0; d < 64; ++d) w2c[d] = W2f[d*64 + c];
    #pragma unroll
    for (int d = 0; d < 64; ++d) w3c[d] = W3[d*64 + c];
    float b1c = b1f[c], b2c = b2f[c], b3c = b3[c];

    #pragma unroll 1
    for (int pp = 0; pp < PTS; ++pp) {
        int i = blockIdx.x*PTS + pp;
        float4 xi = ((const float4*)x0)[i];
        #pragma unroll 4
        for (int k = 0; k < KNN; ++k) {
            int j = idx[i*KNN + k];
            float4 xj = ((const float4*)x0)[j];
            float h = b1c + xi.x*w1c[0] + xi.y*w1c[1] + xi.z*w1c[2] + xi.w*w1c[3]
                          + (xj.x-xi.x)*w1c[4] + (xj.y-xi.y)*w1c[5]
                          + (xj.z-xi.z)*w1c[6] + (xj.w-xi.w)*w1c[7];
            hs0[k*64 + c] = (_Float16)fmaxf(h, 0.0f);
        }
        __syncthreads();
        #pragma unroll 1
        for (int kc = 0; kc < 4; ++kc) {
            float acc[5];
            #pragma unroll
            for (int k5 = 0; k5 < 5; ++k5) acc[k5] = b2c;
            #pragma unroll
            for (int q = 0; q < 8; ++q) {
                #pragma unroll
                for (int k5 = 0; k5 < 5; ++k5) {
                    half8 hv = *(const half8*)&hs0[(kc*5 + k5)*64 + q*8];
                    #pragma unroll
                    for (int jj = 0; jj < 8; ++jj)
                        acc[k5] = fmaf((float)hv[jj], w2c[q*8 + jj], acc[k5]);
                }
            }
            #pragma unroll
            for (int k5 = 0; k5 < 5; ++k5)
                hs1[(kc*5 + k5)*64 + c] = (_Float16)fmaxf(acc[k5], 0.0f);
        }
        __syncthreads();
        float mx = -3.0e38f;
        #pragma unroll 1
        for (int kc = 0; kc < 4; ++kc) {
            float acc[5];
            #pragma unroll
            for (int k5 = 0; k5 < 5; ++k5) acc[k5] = b3c;
            #pragma unroll
            for (int q = 0; q < 8; ++q) {
                #pragma unroll
                for (int k5 = 0; k5 < 5; ++k5) {
                    half8 hv = *(const half8*)&hs1[(kc*5 + k5)*64 + q*8];
                    #pragma unroll
                    for (int jj = 0; jj < 8; ++jj)
                        acc[k5] = fmaf((float)hv[jj], w3c[q*8 + jj], acc[k5]);
                }
            }
            #pragma unroll
            for (int k5 = 0; k5 < 5; ++k5) mx = fmaxf(mx, acc[k5]);
        }
        x1[(size_t)i*64 + c] = mx;
        __syncthreads();
    }
}

// ---------------- K3: uv = x1 @ [Wu | Wv]  (u' gets +bc) ----------------
__global__ __launch_bounds__(256) void k_uv(const float* __restrict__ x1, const float* __restrict__ Wuv,
                                            const float* __restrict__ bc, float* __restrict__ uv)
{
    __shared__ float4 As[64*16];  // 64 rows x 64 cols of x1
    int m0 = blockIdx.x * 64;
    int t  = threadIdx.x;
    #pragma unroll
    for (int l = 0; l < 4; ++l) {
        int lin = l*256 + t;  // 0..1023
        As[lin] = ((const float4*)x1)[(size_t)m0*16 + lin];
    }
    __syncthreads();
    int c = t;  // 0..255
    float acc[64];
    #pragma unroll
    for (int p = 0; p < 64; ++p) acc[p] = 0.f;
    for (int dq = 0; dq < 16; ++dq) {
        float bv0 = Wuv[(dq*4+0)*256 + c];
        float bv1 = Wuv[(dq*4+1)*256 + c];
        float bv2 = Wuv[(dq*4+2)*256 + c];
        float bv3 = Wuv[(dq*4+3)*256 + c];
        #pragma unroll
        for (int p = 0; p < 64; ++p) {
            float4 a = As[p*16 + dq];
            acc[p] += a.x*bv0 + a.y*bv1 + a.z*bv2 + a.w*bv3;
        }
    }
    float badd = (c < 128) ? bc[c] : 0.0f;
    #pragma unroll
    for (int p = 0; p < 64; ++p)
        uv[(size_t)(m0+p)*256 + c] = acc[p] + badd;
}

// ---------------- K4: x2 = u' + max_k v[nbr]  (in-place into u' half of uv) ----------------
__global__ __launch_bounds__(256) void k_x2(const int* __restrict__ idx, float* __restrict__ uv)
{
    int p = blockIdx.x*2 + (threadIdx.x >> 7);
    int c = threadIdx.x & 127;
    float m = -3.0e38f;
    #pragma unroll
    for (int k = 0; k < KNN; ++k) {
        int j = idx[p*KNN + k];
        m = fmaxf(m, uv[(size_t)j*256 + 128 + c]);
    }
    uv[(size_t)p*256 + c] += m;
}

// ---------------- K5: out1 = [x1|x2] @ Wl (+bl), fused per-graph max-pool via atomicMax ----------------
__global__ __launch_bounds__(256) void k_out1(const float* __restrict__ x1, const float* __restrict__ uv,
        const float* __restrict__ Wl, const float* __restrict__ bl, unsigned* __restrict__ out2enc)
{
    __shared__ float As[64][68];
    __shared__ float Bs[64][128];
    int n0 = blockIdx.x * 128;   // 8 col-blocks
    int m0 = blockIdx.y * 64;    // 1024 row-blocks (graph-aligned: 64 | 4096)
    int t  = threadIdx.x;
    int tx = t & 15, ty = t >> 4;
    float acc[4][8];
    #pragma unroll
    for (int i = 0; i < 4; ++i)
        #pragma unroll
        for (int j = 0; j < 8; ++j) acc[i][j] = 0.f;

    for (int kc = 0; kc < 3; ++kc) {
        __syncthreads();
        {
            const float* src = (kc == 0) ? (x1 + (size_t)m0*64) : (uv + (size_t)m0*256 + (kc-1)*64);
            int sstride = (kc == 0) ? 64 : 256;
            #pragma unroll
            for (int l = 0; l < 4; ++l) {
                int lin = l*256 + t;           // 0..1023
                int row = lin >> 4, q = lin & 15;
                float4 v = *(const float4*)(src + (size_t)row*sstride + q*4);
                As[row][q*4+0] = v.x; As[row][q*4+1] = v.y;
                As[row][q*4+2] = v.z; As[row][q*4+3] = v.w;
            }
        }
        #pragma unroll
        for (int l = 0; l < 8; ++l) {
            int lin = l*256 + t;               // 0..2047
            int row = lin >> 5, q = lin & 31;
            float4 v = *(const float4*)(Wl + (size_t)(kc*64 + row)*1024 + n0 + q*4);
            *(float4*)&Bs[row][q*4] = v;
        }
        __syncthreads();
        #pragma unroll 8
        for (int kk = 0; kk < 64; ++kk) {
            float a[4], bvs[8];
            #pragma unroll
            for (int i = 0; i < 4; ++i) a[i] = As[ty*4+i][kk];
            #pragma unroll
            for (int j = 0; j < 8; ++j) bvs[j] = Bs[kk][tx*8+j];
            #pragma unroll
            for (int i = 0; i < 4; ++i)
                #pragma unroll
                for (int j = 0; j < 8; ++j) acc[i][j] += a[i]*bvs[j];
        }
    }
    float cm[8];
    #pragma unroll
    for (int j = 0; j < 8; ++j) {
        float m = acc[0][j];
        #pragma unroll
        for (int i = 1; i < 4; ++i) m = fmaxf(m, acc[i][j]);
        cm[j] = m + bl[n0 + tx*8 + j];
    }
    __syncthreads();
    float* red = &As[0][0];  // reuse: [16][128]
    #pragma unroll
    for (int j = 0; j < 8; ++j) red[ty*128 + tx*8 + j] = cm[j];
    __syncthreads();
    if (ty == 0) {
        int g = m0 >> 12;  // graph id
        #pragma unroll
        for (int j = 0; j < 8; ++j) {
            int cc = tx*8 + j;
            float m = red[cc];
            #pragma unroll
            for (int r2 = 1; r2 < 16; ++r2) m = fmaxf(m, red[r2*128 + cc]);
            atomicMax(&out2enc[g*1024 + n0 + cc], encf(m));
        }
    }
}

// ---------------- K6: per-graph head MLP + log_softmax ----------------
__global__ __launch_bounds__(256) void k_head(const unsigned* __restrict__ out2enc,
        const float* __restrict__ Wa, const float* __restrict__ ba,
        const float* __restrict__ Wb, const float* __restrict__ bb,
        const float* __restrict__ Wo, const float* __restrict__ bo,
        float* __restrict__ out)
{
    __shared__ float s1[1024];
    __shared__ float s2[512];
    __shared__ float s3[256];
    __shared__ float sl[NC];
    int g = blockIdx.x, t = threadIdx.x;
    for (int i = t; i < 1024; i += 256) s1[i] = decf(out2enc[g*1024 + i]);
    __syncthreads();
    for (int cc = t; cc < 512; cc += 256) {
        float a = ba[cc];
        #pragma unroll 8
        for (int d = 0; d < 1024; ++d) a += s1[d] * Wa[(size_t)d*512 + cc];
        s2[cc] = fmaxf(a, 0.f);
    }
    __syncthreads();
    if (t < 256) {
        float a = bb[t];
        #pragma unroll 8
        for (int d = 0; d < 512; ++d) a += s2[d] * Wb[(size_t)d*256 + t];
        s3[t] = fmaxf(a, 0.f);
    }
    __syncthreads();
    if (t < NC) {
        float a = bo[t];
        #pragma unroll 8
        for (int d = 0; d < 256; ++d) a += s3[d] * Wo[d*NC + t];
        sl[t] = a;
    }
    __syncthreads();
    if (t < 64) {
        float v = (t < NC) ? sl[t] : -3.0e38f;
        float m = v;
        #pragma unroll
        for (int o2 = 32; o2 >= 1; o2 >>= 1) m = fmaxf(m, __shfl_xor(m, o2));
        float e = (t < NC) ? expf(sl[t] - m) : 0.f;
        float s = e;
        #pragma unroll
        for (int o2 = 32; o2 >= 1; o2 >>= 1) s += __shfl_xor(s, o2);
        float ls = logf(s) + m;
        if (t < NC) out[g*NC + t] = sl[t] - ls;
    }
}

// ---------------- launch ----------------
extern "C" void kernel_launch(void* const* d_in, const int* in_sizes, int n_in,
                              void* d_out, int out_size, void* d_ws, size_t ws_size,
                              hipStream_t stream)
{
    const float* pos  = (const float*)d_in[0];
    const float* feat = (const float*)d_in[1];
    const float* W1 = (const float*)d_in[2];
    const float* b1 = (const float*)d_in[3];
    const float* g1 = (const float*)d_in[4];
    const float* be1= (const float*)d_in[5];
    const float* m1 = (const float*)d_in[6];
    const float* v1 = (const float*)d_in[7];
    const float* W2 = (const float*)d_in[8];
    const float* b2 = (const float*)d_in[9];
    const float* g2 = (const float*)d_in[10];
    const float* be2= (const float*)d_in[11];
    const float* m2 = (const float*)d_in[12];
    const float* v2 = (const float*)d_in[13];
    const float* W3 = (const float*)d_in[14];
    const float* b3 = (const float*)d_in[15];
    const float* Wc = (const float*)d_in[16];
    const float* bc = (const float*)d_in[17];
    const float* Wl = (const float*)d_in[18];
    const float* bl = (const float*)d_in[19];
    const float* Wa = (const float*)d_in[20];
    const float* ba = (const float*)d_in[21];
    const float* Wb = (const float*)d_in[22];
    const float* bb = (const float*)d_in[23];
    const float* Wo = (const float*)d_in[24];
    const float* bo = (const float*)d_in[25];
    float* out = (float*)d_out;

    char* ws = (char*)d_ws;
    float* x0  = (float*)(ws + O_X0);
    int*   idx = (int*)  (ws + O_IDX);
    float* x1  = (float*)(ws + O_X1);
    float* uv  = (float*)(ws + O_UV);
    u64*   pk  = (u64*)  (ws + O_UV);   // packed knn partials overlay uv (dead until k_uv)
    float* W1f = (float*)(ws + O_WT);
    float* b1f = W1f + 512;
    float* W2f = b1f + 64;
    float* b2f = W2f + 4096;
    float* Wuv = b2f + 64;
    unsigned* out2enc = (unsigned*)(Wuv + 64*256);

    k_fold <<<1, 256, 0, stream>>>(W1,b1,g1,be1,m1,v1, W2,b2,g2,be2,m2,v2, Wc,
                                   W1f,b1f,W2f,b2f,Wuv,out2enc);
    k_x0   <<<NPTS/256, 256, 0, stream>>>(pos, feat, x0);
    k_knn_part <<<BGRAPH*16*SEG, 256, 0, stream>>>(x0, pk);
    k_knn_merge<<<NPTS/256, 256, 0, stream>>>(pk, idx);
    k_conv1<<<NPTS/PTS, 64, 0, stream>>>(x0, idx, W1f, b1f, W2f, b2f, W3, b3, x1);
    k_uv   <<<NPTS/64, 256, 0, stream>>>(x1, Wuv, bc, uv);
    k_x2   <<<NPTS/2, 256, 0, stream>>>(idx, uv);
    dim3 g5(8, 1024);
    k_out1 <<<g5, 256, 0, stream>>>(x1, uv, Wl, bl, out2enc);
    k_head <<<BGRAPH, 256, 0, stream>>>(out2enc, Wa,ba,Wb,bb,Wo,bo, out);
}